// Round 2
// baseline (255.286 us; speedup 1.0000x reference)
//
#include <hip/hip_runtime.h>

// out[b, n] = sum_k x[b,k] * w[n,k];  B=8, K=4096, N=11008, fp32.
// HBM-bound on the 180 MB weight stream (floor ~29 us at 6.3 TB/s).
// Round-2 design: no LDS, no barriers. Each wave owns 4 output rows across
// full K. Per k-step: 12 independent 16B loads (8 x from L2-hot 128 KB x,
// 4 weight), 128 FMAs. unroll-1 + launch_bounds(256,4) keep VGPRs <= 128
// so 16 waves/CU provide the in-flight bytes that round 1 lacked.

#define BATCH 8
#define KDIM  4096
#define NDIM  11008
#define BLOCK 256
#define RPW   4                 // rows per wave
#define RPB   16                // 4 waves * 4 rows
#define KSTEPS (KDIM / 4 / 64)  // 16 float4-steps per row per lane

__global__ __launch_bounds__(BLOCK, 4)
void ActivationSparseLinear_4982162063725_kernel(const float* __restrict__ x,
                                                 const float* __restrict__ w,
                                                 float* __restrict__ out) {
    const int tid  = threadIdx.x;
    const int lane = tid & 63;
    const int wave = tid >> 6;
    const int n0   = blockIdx.x * RPB + wave * RPW;

    const float4* x4 = (const float4*)x;   // [BATCH][KDIM/4]
    const float4* w4 = (const float4*)w;   // [NDIM][KDIM/4]

    float acc[RPW][BATCH];
#pragma unroll
    for (int r = 0; r < RPW; ++r)
#pragma unroll
        for (int b = 0; b < BATCH; ++b) acc[r][b] = 0.0f;

#pragma unroll 1
    for (int j = 0; j < KSTEPS; ++j) {
        const int k4 = j * 64 + lane;

        float4 xv[BATCH];
#pragma unroll
        for (int b = 0; b < BATCH; ++b)
            xv[b] = x4[b * (KDIM / 4) + k4];          // L2-resident, coalesced

        float4 wv[RPW];
#pragma unroll
        for (int r = 0; r < RPW; ++r)
            wv[r] = w4[(size_t)(n0 + r) * (KDIM / 4) + k4];  // HBM stream, coalesced 1KB/wave

#pragma unroll
        for (int r = 0; r < RPW; ++r)
#pragma unroll
            for (int b = 0; b < BATCH; ++b)
                acc[r][b] += wv[r].x * xv[b].x + wv[r].y * xv[b].y
                           + wv[r].z * xv[b].z + wv[r].w * xv[b].w;
    }

    // Reduce each of the 32 (row, batch) partials across the 64-lane wave.
#pragma unroll
    for (int r = 0; r < RPW; ++r)
#pragma unroll
        for (int b = 0; b < BATCH; ++b) {
            float v = acc[r][b];
#pragma unroll
            for (int off = 32; off > 0; off >>= 1)
                v += __shfl_xor(v, off, 64);
            if (lane == 0)
                out[(size_t)b * NDIM + (n0 + r)] = v;
        }
}

extern "C" void kernel_launch(void* const* d_in, const int* in_sizes, int n_in,
                              void* d_out, int out_size, void* d_ws, size_t ws_size,
                              hipStream_t stream) {
    const float* x = (const float*)d_in[0];   // (8, 1, 4096) fp32
    const float* w = (const float*)d_in[1];   // (11008, 4096) fp32
    float* out = (float*)d_out;               // (8, 1, 11008) fp32

    dim3 grid(NDIM / RPB);                    // 688 blocks, exact fit
    ActivationSparseLinear_4982162063725_kernel<<<grid, BLOCK, 0, stream>>>(x, w, out);
}